// Round 1
// 237.453 us; speedup vs baseline: 1.0311x; 1.0311x over previous
//
#include <hip/hip_runtime.h>

// SocialPoolingLayer: fused edge-MLP (relu(pair@W1+b1)@W2+b2, sigmoid gate, elemwise
// product) + scatter-mean by src node.
// Round 10 (VALU-cut round; R9 measured VALUBusy=64%, MfmaUtil=12% -> issue-bound):
// (a) gate path pre-scaled by log2(e) in prep (W2@Wg frags + bgp), sigmoid computed as
//     rcp(1+exp2(-x)) with raw v_exp_f32/v_rcp_f32 -- kills 16x IEEE-div sequences
//     (~160 VALU/wave; -O3 has no fast-math so a/b was div_scale/div_fmas/div_fixup);
// (b) segmented flush rewritten: per-lane in-place PREFIX sums (12 adds) + one __ballot
//     boundary mask + scalar ctz segment loop with readlane -- replaces the 16-iter
//     serial scan (16 ds_reads + per-iter cmp/saveexec/masked-adds churn);
// (c) staging 1/max(cnt,1) via v_rcp_f32.
// Workspace layout byte-identical to R5..R9's proven extent. Packed (src<<16|dst)
// sorted array kept from R8 (FETCH 127->30MB win).

typedef unsigned short ushort_t;
typedef __attribute__((ext_vector_type(8))) short     bf16x8;   // 8 bf16 = 4 VGPRs
typedef __attribute__((ext_vector_type(8))) unsigned short u16x8;
typedef __attribute__((ext_vector_type(4))) float     f32x4;

constexpr int D        = 64;
constexpr int TILE     = 64;     // edges per block (4 waves x 16 edges)
constexpr int BLOCK    = 256;
constexpr int NFRAG    = 32;     // 16 (W1) + 8 (W2) + 8 (W2@Wg) B-fragments
constexpr int SLAB_B   = 4352;   // per-wave slab: 16 rows x 272 B
constexpr int PAIR_STR = 136;    // pair row stride (bf16): 272 B
constexpr int H_STR    = 72;     // h row stride (bf16): 144 B
constexpr float LOG2E  = 1.4426950408889634f;

static __device__ __forceinline__ ushort_t f2bf(float f) {
    union { float f; unsigned int u; } v; v.f = f;
    const unsigned int r = v.u + 0x7FFFu + ((v.u >> 16) & 1u);   // RNE
    return (ushort_t)(r >> 16);
}

#if __has_builtin(__builtin_amdgcn_exp2f)
static __device__ __forceinline__ float fexp2(float x) { return __builtin_amdgcn_exp2f(x); }
#else
static __device__ __forceinline__ float fexp2(float x) {
    float r; asm("v_exp_f32 %0, %1" : "=v"(r) : "v"(x)); return r;
}
#endif
#if __has_builtin(__builtin_amdgcn_rcpf)
static __device__ __forceinline__ float frcp(float x) { return __builtin_amdgcn_rcpf(x); }
#else
static __device__ __forceinline__ float frcp(float x) {
    float r; asm("v_rcp_f32 %0, %1" : "=v"(r) : "v"(x)); return r;
}
#endif

// ---- prep: pack + W2Wg + bg' + emb->bf16 + histogram + summed-zero, one dispatch ----
// Weight fragment layout (verified R3): frag f, lane l, elem j -> W[k][n],
// k = kc*32 + (l>>4)*8 + j, n = nt*16 + (l&15).
// f in [0,16): W1; [16,24): W2; [24,32): (W2@Wg)*log2e (computed+scaled here -- lets
// the main kernel evaluate sigmoid with a bare v_exp_f32).

__global__ void prep_kernel(const float* __restrict__ W1, const float* __restrict__ W2,
                            const float* __restrict__ Wg,
                            const float* __restrict__ b2, const float* __restrict__ bg,
                            const float* __restrict__ emb, const int* __restrict__ ei,
                            ushort_t* __restrict__ wpack, float* __restrict__ bgp,
                            ushort_t* __restrict__ emb_bf, int* __restrict__ cnt,
                            float* __restrict__ summed,
                            int total_emb, int cvt_blocks, int e4blocks, int E) {
    const int bid = blockIdx.x;
    if (bid < 64) {                              // 64*256 == NFRAG*512: weight packing
        const int t = bid * 256 + threadIdx.x;
        const int f = t >> 9;
        const int l = (t >> 3) & 63;
        const int j = t & 7;
        const int k = ((f < 16) ? (f & 3) : ((f - 16) & 1)) * 32 + (l >> 4) * 8 + j;
        const int n = ((f < 16) ? (f >> 2) : (((f & 7)) >> 1)) * 16 + (l & 15);
        float v;
        if (f < 16)      v = W1[k * 64 + n];
        else if (f < 24) v = W2[k * 64 + n];
        else {                                   // (W2@Wg)[k][n] * log2(e)
            float s = 0.f;
            const float* wr = W2 + k * 64;
#pragma unroll 8
            for (int m = 0; m < 64; ++m) s += wr[m] * Wg[m * 64 + n];
            v = s * LOG2E;
        }
        wpack[t] = f2bf(v);
    } else if (bid < 64 + cvt_blocks) {          // node_emb -> bf16
        const int idx  = (bid - 64) * 256 + threadIdx.x;
        const int base = idx * 8;
        if (base < total_emb) {
            const float4 a = *(const float4*)(emb + base);
            const float4 b = *(const float4*)(emb + base + 4);
            u16x8 p;
            p[0]=f2bf(a.x); p[1]=f2bf(a.y); p[2]=f2bf(a.z); p[3]=f2bf(a.w);
            p[4]=f2bf(b.x); p[5]=f2bf(b.y); p[6]=f2bf(b.z); p[7]=f2bf(b.w);
            *(u16x8*)(emb_bf + base) = p;
        }
    } else if (bid == 64 + cvt_blocks) {         // bg' = (b2@Wg + bg) * log2(e)  (fp32)
        const int n = threadIdx.x;
        if (n < 64) {
            float s = bg[n];
#pragma unroll 8
            for (int m = 0; m < 64; ++m) s += b2[m] * Wg[m * 64 + n];
            bgp[n] = s * LOG2E;
        }
    } else if (bid < 65 + cvt_blocks + e4blocks) {   // edge histogram by src
        const int e = ((bid - 65 - cvt_blocks) * 256 + threadIdx.x) * 4;
        if (e + 3 < E) {
            const int4 v = *(const int4*)(ei + e);
            atomicAdd(&cnt[v.x], 1); atomicAdd(&cnt[v.y], 1);
            atomicAdd(&cnt[v.z], 1); atomicAdd(&cnt[v.w], 1);
        } else {
            for (int k = e; k < E; ++k) atomicAdd(&cnt[ei[k]], 1);
        }
    } else {                                     // zero summed (consumed 2 nodes later)
        const int idx  = (bid - 65 - cvt_blocks - e4blocks) * 256 + threadIdx.x;
        const int base = idx * 4;
        if (base < total_emb)
            *(float4*)(summed + base) = (float4){0.f, 0.f, 0.f, 0.f};
    }
}

// ---------------- scan: per-block exclusive offsets + block sums ----------

__global__ void scan_block(const int* __restrict__ cnt, int* __restrict__ off,
                           int* __restrict__ bsum, int N) {
    __shared__ int s[256];
    const int t = threadIdx.x, i = blockIdx.x * 256 + t;
    const int x = (i < N) ? cnt[i] : 0;
    s[t] = x; __syncthreads();
    for (int d = 1; d < 256; d <<= 1) {
        const int v = (t >= d) ? s[t - d] : 0;
        __syncthreads();
        s[t] += v;
        __syncthreads();
    }
    if (i < N) off[i] = s[t] - x;                 // block-local exclusive prefix
    if (t == 255) bsum[blockIdx.x] = s[255];
}

// scatter with inline bsum prefix (nb <= 256); off[] doubles as insertion cursor.
// Writes packed (src<<16)|dst per slot -- requires N < 65536.
__global__ void scatter_idx(const int* __restrict__ ei, int* __restrict__ off,
                            const int* __restrict__ bsum, unsigned* __restrict__ sorted,
                            int E, int nb) {
    __shared__ int pref[256];
    const int t = threadIdx.x;
    const int x = (t < nb) ? bsum[t] : 0;
    pref[t] = x; __syncthreads();
    for (int d = 1; d < 256; d <<= 1) {
        const int v = (t >= d) ? pref[t - d] : 0;
        __syncthreads();
        pref[t] += v;
        __syncthreads();
    }
    // pref[] inclusive prefix of bsum; exclusive for block b is pref[b-1] (0 if b==0)
    const int e = (blockIdx.x * blockDim.x + t) * 4;
    if (e + 3 < E) {
        const int4 v = *(const int4*)(ei + e);        // src
        const int4 d = *(const int4*)(ei + E + e);    // dst
        const int bx = v.x >> 8, by = v.y >> 8, bz = v.z >> 8, bw = v.w >> 8;
        sorted[(bx ? pref[bx - 1] : 0) + atomicAdd(&off[v.x], 1)] =
            ((unsigned)v.x << 16) | (unsigned)d.x;
        sorted[(by ? pref[by - 1] : 0) + atomicAdd(&off[v.y], 1)] =
            ((unsigned)v.y << 16) | (unsigned)d.y;
        sorted[(bz ? pref[bz - 1] : 0) + atomicAdd(&off[v.z], 1)] =
            ((unsigned)v.z << 16) | (unsigned)d.z;
        sorted[(bw ? pref[bw - 1] : 0) + atomicAdd(&off[v.w], 1)] =
            ((unsigned)v.w << 16) | (unsigned)d.w;
    } else {
        for (int k = e; k < E; ++k) {
            const int s = ei[k], b = s >> 8;
            sorted[(b ? pref[b - 1] : 0) + atomicAdd(&off[s], 1)] =
                ((unsigned)s << 16) | (unsigned)ei[E + k];
        }
    }
}

// ---------------- fused MFMA MLP + register segmented scatter (barrier-free) --------
// Wave w exclusively owns its 4352B slab + srcIds/rcS rows 16w..16w+15. All LDS
// dependencies are intra-wave (issue-order DS pipe + compiler lgkmcnt waits), so
// pair -> h reuse one slab with no __syncthreads. Gated values never touch LDS:
// the segmented reduction now runs as per-lane prefix sums + a scalar segment loop
// driven by a __ballot boundary mask; cross-quad butterfly only at flush.

__global__ __launch_bounds__(BLOCK, 8)
void edge_mlp_mfma(const ushort_t* __restrict__ emb_bf,   // [N][64] bf16
                   const unsigned* __restrict__ sorted,   // packed (src<<16)|dst, sorted
                   const ushort_t* __restrict__ wpack,    // 32 packed B-frags
                   const float* __restrict__ b1, const float* __restrict__ b2,
                   const float* __restrict__ bgp,         // (b2@Wg + bg) * log2e
                   const int*   __restrict__ cnt,         // per-node edge counts
                   float* __restrict__ summed,            // [N][D] pre-zeroed
                   int E)
{
    __shared__ char  slab[4][SLAB_B];    // 17408 B: per-wave pair then h
    __shared__ int   srcIds[TILE];
    __shared__ float rcS[TILE];

    const int tid = threadIdx.x;

    // ---- stage: one packed 4B load -> two 128B row gathers into per-wave slab ----
    {
        const int e = tid >> 2, q4 = tid & 3;     // e: edge slot 0..63, q4: 16-elem quarter
        ushort_t* prow = (ushort_t*)&slab[e >> 4][(e & 15) * (PAIR_STR * 2)];
        const int ide = blockIdx.x * TILE + e;
        if (ide < E) {
            const unsigned p = sorted[ide];
            const int s  = (int)(p >> 16);
            const int dn = (int)(p & 0xFFFFu);
            if (q4 == 0) { srcIds[e] = s; rcS[e] = frcp(fmaxf((float)cnt[s], 1.0f)); }
            const ushort_t* sr = emb_bf + (size_t)s  * D + q4 * 16;
            const ushort_t* dr = emb_bf + (size_t)dn * D + q4 * 16;
            *(u16x8*)&prow[q4 * 16]          = *(const u16x8*)sr;
            *(u16x8*)&prow[q4 * 16 + 8]      = *(const u16x8*)(sr + 8);
            *(u16x8*)&prow[64 + q4 * 16]     = *(const u16x8*)dr;
            *(u16x8*)&prow[64 + q4 * 16 + 8] = *(const u16x8*)(dr + 8);
        } else {
            if (q4 == 0) { srcIds[e] = -1; rcS[e] = 1.0f; }
            const u16x8 z = {0,0,0,0,0,0,0,0};
            *(u16x8*)&prow[q4 * 16]          = z;
            *(u16x8*)&prow[q4 * 16 + 8]      = z;
            *(u16x8*)&prow[64 + q4 * 16]     = z;
            *(u16x8*)&prow[64 + q4 * 16 + 8] = z;
        }
    }

    const int w    = tid >> 6;           // wave id: owns slab[w] + rows 16w..16w+15
    const int ln   = tid & 63;
    const int quad = ln >> 4;
    const int cn   = ln & 15;
    ushort_t* pairW = (ushort_t*)slab[w];   // [16][136]
    ushort_t* hW    = (ushort_t*)slab[w];   // [16][72]  (overwrites pair after a1 reads)

    // ---- GEMM1: h = relu(pair @ W1 + b1), M=16 K=128 N=64 (kc-outer) ----
    f32x4 acc1[4];
#pragma unroll
    for (int nt = 0; nt < 4; ++nt) {
        const float b = b1[nt * 16 + cn];
        acc1[nt] = (f32x4){b, b, b, b};
    }
#pragma unroll
    for (int kc = 0; kc < 4; ++kc) {
        const bf16x8 a = *(const bf16x8*)&pairW[cn * PAIR_STR + kc * 32 + quad * 8];
#pragma unroll
        for (int nt = 0; nt < 4; ++nt) {
            const bf16x8 bf = *(const bf16x8*)(wpack + ((nt * 4 + kc) * 64 + ln) * 8);
            acc1[nt] = __builtin_amdgcn_mfma_f32_16x16x32_bf16(a, bf, acc1[nt], 0, 0, 0);
        }
    }
#pragma unroll
    for (int nt = 0; nt < 4; ++nt)
#pragma unroll
        for (int r = 0; r < 4; ++r)
            hW[(quad * 4 + r) * H_STR + nt * 16 + cn] = f2bf(fmaxf(acc1[nt][r], 0.f));

    // ---- GEMM2+3 fused (kc-outer): interaction = h@W2+b2 ; gate_pre = h@(W2Wg*log2e)+bg' ----
    f32x4 acc2[4], accg[4];
#pragma unroll
    for (int nt = 0; nt < 4; ++nt) {
        const float b  = b2 [nt * 16 + cn];
        const float bG = bgp[nt * 16 + cn];
        acc2[nt] = (f32x4){b, b, b, b};
        accg[nt] = (f32x4){bG, bG, bG, bG};
    }
#pragma unroll
    for (int kc = 0; kc < 2; ++kc) {
        const bf16x8 a = *(const bf16x8*)&hW[cn * H_STR + kc * 32 + quad * 8];
#pragma unroll
        for (int nt = 0; nt < 4; ++nt) {
            const bf16x8 bf2 = *(const bf16x8*)(wpack + ((16 + nt * 2 + kc) * 64 + ln) * 8);
            const bf16x8 bfg = *(const bf16x8*)(wpack + ((24 + nt * 2 + kc) * 64 + ln) * 8);
            acc2[nt] = __builtin_amdgcn_mfma_f32_16x16x32_bf16(a, bf2, acc2[nt], 0, 0, 0);
            accg[nt] = __builtin_amdgcn_mfma_f32_16x16x32_bf16(a, bfg, accg[nt], 0, 0, 0);
        }
    }

    // ---- gated = interaction * sigmoid(gate_pre), folded into per-lane PREFIX sums ----
    // accg is pre-scaled by log2(e): sigmoid(x) = rcp(1 + 2^-x_hat). rcp/exp2 approx
    // (~1e-7 rel) is far below bf16 noise. P[nt][r] = sum of gated rows 4q..4q+r.
    float P[4][4];
#pragma unroll
    for (int nt = 0; nt < 4; ++nt) {
#pragma unroll
        for (int r = 0; r < 4; ++r) {
            const float ex = fexp2(-accg[nt][r]);
            P[nt][r] = acc2[nt][r] * frcp(1.0f + ex);
        }
        P[nt][1] += P[nt][0];
        P[nt][2] += P[nt][1];
        P[nt][3] += P[nt][2];
    }

    // ---- segmented scatter: ballot boundary mask + scalar segment loop ----
    // bit i of bmask: row i starts a new src segment (bit0 forced). Mean degree 16
    // => ~2 segments/wave, so per-segment cost (prefix-diff select + butterfly +
    // one 64-lane atomic) replaces the old 16-iteration serial scan.
    {
        const int   rbase  = 16 * w;
        const int   myRow  = ln & 15;
        const int   mySrc  = srcIds[rbase + myRow];
        const float myRc   = rcS[rbase + myRow];
        const int   prevSrc = srcIds[rbase + ((myRow + 15) & 15)];   // wraps; bit0 forced
        unsigned bmask = ((unsigned)__ballot(mySrc != prevSrc) & 0xFFFFu) | 1u;
        const int q4r = 4 * quad;
        while (bmask) {
            const int a = __builtin_ctz(bmask);
            bmask &= (bmask - 1u);
            const int b = bmask ? __builtin_ctz(bmask) : 16;
            const int sseg = __builtin_amdgcn_readlane(mySrc, a);
            if (sseg >= 0) {
                // lane's row range for this segment: [a,b) ∩ [4q,4q+4), as prefix diff
                const int lo  = a - q4r, hi = b - q4r;
                const int clo = lo < 0 ? 0 : (lo > 4 ? 4 : lo);
                const int chi = hi < 0 ? 0 : (hi > 4 ? 4 : hi);
                const bool ge1 = chi > 1, ge2 = chi > 2, ge3 = chi > 3;
                const bool l0 = clo > 0, l1 = clo > 1, l2 = clo > 2;
                const bool valid = chi > clo;
                float t[4];
#pragma unroll
                for (int nt = 0; nt < 4; ++nt) {
                    const float sh = ge2 ? (ge3 ? P[nt][3] : P[nt][2])
                                         : (ge1 ? P[nt][1] : P[nt][0]);
                    const float sl = l1 ? (l2 ? P[nt][2] : P[nt][1])
                                        : (l0 ? P[nt][0] : 0.f);
                    t[nt] = valid ? sh - sl : 0.f;
                }
                t[0] += __shfl_xor(t[0], 16); t[0] += __shfl_xor(t[0], 32);
                t[1] += __shfl_xor(t[1], 16); t[1] += __shfl_xor(t[1], 32);
                t[2] += __shfl_xor(t[2], 16); t[2] += __shfl_xor(t[2], 32);
                t[3] += __shfl_xor(t[3], 16); t[3] += __shfl_xor(t[3], 32);
                const float tot = (quad < 2) ? (quad == 0 ? t[0] : t[1])
                                             : (quad == 2 ? t[2] : t[3]);
                const float rc = __uint_as_float(
                    __builtin_amdgcn_readlane(__float_as_uint(myRc), a));
                unsafeAtomicAdd(&summed[(size_t)sseg * D + ln], tot * rc);
            }
        }
    }
}

extern "C" void kernel_launch(void* const* d_in, const int* in_sizes, int n_in,
                              void* d_out, int out_size, void* d_ws, size_t ws_size,
                              hipStream_t stream) {
    const float* node_emb   = (const float*)d_in[0];
    const int*   edge_index = (const int*)d_in[1];
    const float* W1 = (const float*)d_in[2];
    const float* b1 = (const float*)d_in[3];
    const float* W2 = (const float*)d_in[4];
    const float* b2 = (const float*)d_in[5];
    const float* Wg = (const float*)d_in[6];
    const float* bg = (const float*)d_in[7];

    const int N = in_sizes[0] / D;
    const int E = in_sizes[1] / 2;
    const int total_emb = N * D;

    // ws layout == R5..R9's proven extent (10,034,048 B for N=50000, E=800000):
    // cnt[N] | off[N] | bsum[256] | sorted[E u32] | bgp[64 f32] | wpack[16K bf16] | emb_bf
    int* cnt    = (int*)d_ws;
    int* off    = cnt + N;
    int* bsum   = off + N;
    unsigned* sorted = (unsigned*)(bsum + 256);
    float* bgp  = (float*)(sorted + E);
    ushort_t* wpack  = (ushort_t*)(bgp + 64);
    ushort_t* emb_bf = wpack + NFRAG * 512;

    float* summed = (float*)d_out;

    hipMemsetAsync(cnt, 0, sizeof(int) * (size_t)N, stream);   // must precede prep's hist

    const int cvt_blocks = (total_emb / 8 + 255) / 256;
    const int e4blocks   = ((E + 3) / 4 + 255) / 256;
    const int zblocks    = (total_emb / 4 + 255) / 256;
    prep_kernel<<<64 + cvt_blocks + 1 + e4blocks + zblocks, 256, 0, stream>>>(
        W1, W2, Wg, b2, bg, node_emb, edge_index,
        wpack, bgp, emb_bf, cnt, summed, total_emb, cvt_blocks, e4blocks, E);

    const int nblocks = (N + 255) / 256;   // 196 (must be <= 256 for inline prefix)
    scan_block <<<nblocks, 256, 0, stream>>>(cnt, off, bsum, N);
    scatter_idx<<<e4blocks, 256, 0, stream>>>(edge_index, off, bsum, sorted, E, nblocks);

    const int ntiles = (E + TILE - 1) / TILE;
    edge_mlp_mfma<<<ntiles, BLOCK, 0, stream>>>(emb_bf, sorted, wpack,
                                                b1, b2, bgp, cnt, summed, E);
}